// Round 5
// baseline (737.947 us; speedup 1.0000x reference)
//
#include <hip/hip_runtime.h>
#include <cstdint>

#define B_ 128
#define T_ 1024
#define D_ 256
#define U_ 48

// Guaranteed 3-input max (exact, same result as two v_max_f32).
__device__ __forceinline__ float max3f(float a, float b, float c) {
    float d;
    asm("v_max3_f32 %0, %1, %2, %3" : "=v"(d) : "v"(a), "v"(b), "v"(c));
    return d;
}

// Full-wave rotate-by-1 via DPP (wave_ror:1, ctrl 0x13C). Full-rate VALU.
// Direction (src[n+1] vs src[n-1]) is probed at runtime; tr[] indexing adapts.
__device__ __forceinline__ float ror1f(float x) {
    return __int_as_float(__builtin_amdgcn_mov_dpp(__float_as_int(x), 0x13C, 0xF, 0xF, true));
}

// ---------------------------------------------------------------------------
// K1: logits[row][u] = sum_d x[row][d]*kernel[d][u] + bias[u].
// (unchanged — d-blocked, K in LDS, own-line loads)
// ---------------------------------------------------------------------------
__global__ __launch_bounds__(256, 1) void k_logits(const float* __restrict__ x,
                                                   const float* __restrict__ kern,
                                                   const float* __restrict__ bias,
                                                   float* __restrict__ logits) {
    __shared__ float K[D_ * U_];   // 48 KB
    __shared__ float bsh[U_];
    const int tid = threadIdx.x;
    for (int i = tid; i < D_ * U_; i += 256) K[i] = kern[i];
    if (tid < U_) bsh[tid] = bias[tid];
    __syncthreads();

    const long row0 = (long)blockIdx.x * 256 + tid;      // 0..65535
    const long row1 = row0 + (long)B_ * T_ / 2;          // +65536
    const float4* xr0 = (const float4*)(x + row0 * D_);
    const float4* xr1 = (const float4*)(x + row1 * D_);

    float a0[U_], a1[U_];
#pragma unroll
    for (int u = 0; u < U_; ++u) { a0[u] = 0.0f; a1[u] = 0.0f; }

#pragma unroll 1
    for (int blk = 0; blk < D_ / 32; ++blk) {            // 8 chunks of 128 B
        float4 xa[8], xb[8];
#pragma unroll
        for (int i = 0; i < 8; ++i) xa[i] = xr0[blk * 8 + i];  // own line
#pragma unroll
        for (int i = 0; i < 8; ++i) xb[i] = xr1[blk * 8 + i];  // own line

#pragma unroll
        for (int i = 0; i < 8; ++i) {
            const int d4 = blk * 8 + i;
            const float xc0[4] = {xa[i].x, xa[i].y, xa[i].z, xa[i].w};
            const float xc1[4] = {xb[i].x, xb[i].y, xb[i].z, xb[i].w};
#pragma unroll
            for (int c = 0; c < 4; ++c) {
                const float4* kp = (const float4*)&K[(d4 * 4 + c) * U_];
                const float s0 = xc0[c], s1 = xc1[c];
#pragma unroll
                for (int u4 = 0; u4 < U_ / 4; ++u4) {
                    float4 kv = kp[u4];
                    a0[u4*4+0] += s0 * kv.x;  a1[u4*4+0] += s1 * kv.x;
                    a0[u4*4+1] += s0 * kv.y;  a1[u4*4+1] += s1 * kv.y;
                    a0[u4*4+2] += s0 * kv.z;  a1[u4*4+2] += s1 * kv.z;
                    a0[u4*4+3] += s0 * kv.w;  a1[u4*4+3] += s1 * kv.w;
                }
            }
        }
    }

    float4* o0 = (float4*)(logits + row0 * U_);
    float4* o1 = (float4*)(logits + row1 * U_);
#pragma unroll
    for (int i = 0; i < U_ / 4; ++i) {
        float4 v0, v1;
        v0.x = a0[i*4+0] + bsh[i*4+0];  v1.x = a1[i*4+0] + bsh[i*4+0];
        v0.y = a0[i*4+1] + bsh[i*4+1];  v1.y = a1[i*4+1] + bsh[i*4+1];
        v0.z = a0[i*4+2] + bsh[i*4+2];  v1.z = a1[i*4+2] + bsh[i*4+2];
        v0.w = a0[i*4+3] + bsh[i*4+3];  v1.w = a1[i*4+3] + bsh[i*4+3];
        o0[i] = v0;
        o1[i] = v1;
    }
}

// ---------------------------------------------------------------------------
// Max-plus body, R11: systolic DPP rotation. s~ is the 64-lane state vector
// (lanes 48..63 = -3e38, T~ rows 48..63 = 0 -> padded candidates never win;
// exact). Two 32-rotation chains: A from s~ itself, B from s~ rotated by 32
// (one ds_bpermute, latency hidden under the A half). tr[k] holds the
// matching diagonal of T~ per lane (loaded once, direction-probed).
// 62 mov_dpp + 64 add + 31 max3 + 1 fmax + 1 cndmask + 1 bpermute per step.
// Candidates = single IEEE adds of same operands as ref; max reassoc exact.
// ---------------------------------------------------------------------------
__device__ __forceinline__ float maxplus_dpp(float state, const float* tr,
                                             int lane, int baddr) {
    const float rsrc = (lane < U_) ? state : -3.0e38f;       // pad lanes 48..63
    const int rbi = __builtin_amdgcn_ds_bpermute(baddr, __float_as_int(rsrc));

    float rA = rsrc;                       // rotation 0
    float c0 = rA + tr[0];
    rA = ror1f(rA);                        // rotation 1
    float c1 = rA + tr[1];
    float m = fmaxf(c0, c1);
#pragma unroll
    for (int k = 2; k < 32; k += 2) {
        rA = ror1f(rA); float ca = rA + tr[k];
        rA = ror1f(rA); float cb = rA + tr[k + 1];
        m = max3f(m, ca, cb);
    }
    float rB = __int_as_float(rbi);        // rotation 32 (lgkmcnt wait here)
    float d0 = rB + tr[32];
    rB = ror1f(rB);                        // rotation 33
    float d1 = rB + tr[33];
    m = max3f(m, d0, d1);
#pragma unroll
    for (int k = 34; k < 64; k += 2) {
        rB = ror1f(rB); float ca = rB + tr[k];
        rB = ror1f(rB); float cb = rB + tr[k + 1];
        m = max3f(m, ca, cb);
    }
    return m;
}

// Per-lane tr table: tr[k] = T~[(lane + dirm*k) & 63][u], where dirm is the
// probed DPP direction (+1 or 63 == -1 mod 64). Rows >= 48 are 0.
__device__ __forceinline__ void load_tr(const float* __restrict__ trans,
                                        float* tr, int lane, int u) {
    const int p = __builtin_amdgcn_mov_dpp(lane, 0x13C, 0xF, 0xF, true);
    const int dirm = (p - lane) & 63;      // probe: ror1 semantics
#pragma unroll
    for (int k = 0; k < 64; ++k) {
        const int w = (lane + dirm * k) & 63;
        tr[k] = (w < U_) ? trans[w * U_ + u] : 0.0f;
    }
}

// ---------------------------------------------------------------------------
// K2: Viterbi forward. One wave per batch chain; lane u owns delta[u];
// lanes 48..63 carry -inf padding (stores predicated). No LDS round trip.
// ---------------------------------------------------------------------------
__global__ __launch_bounds__(64, 1) void k_forward(const float* __restrict__ trans,
                                                   const float* __restrict__ logits,
                                                   float* __restrict__ delta) {
    const int lane = threadIdx.x;
    const int b = blockIdx.x;
    const int u = (lane < U_) ? lane : (U_ - 1);
    const int baddr = ((lane + 32) & 63) * 4;   // bpermute src lane (+-32 == 32 mod 64)

    float tr[64];
    load_tr(trans, tr, lane, u);

    const float* lin = logits + (long)b * T_ * U_;
    float* dout = delta + (long)b * T_ * U_;

    float state = lin[u];                 // delta_0 = logits row 0
    if (lane < U_) dout[u] = state;

    float pf[8];
#pragma unroll
    for (int i = 0; i < 8; ++i) pf[i] = lin[(1 + i) * U_ + u];  // rows 1..8

    const float* lp = lin + 9 * U_ + u;   // prefetch base: row tb+8 for tb=1
    float* dp = dout + 1 * U_ + u;        // store base: row tb

#pragma unroll 1
    for (int g = 0; g < 127; ++g) {       // t = 1+8g .. 8+8g  (1..1016)
#pragma unroll
        for (int j = 0; j < 8; ++j) {
            const float logit = pf[j];
            pf[j] = lp[j * U_];                       // imm offset j*192 B
            const float m = maxplus_dpp(state, tr, lane, baddr);
            state = logit + m;                        // exact ref op order
            if (lane < U_) dp[j * U_] = state;        // imm offset j*192 B
        }
        lp += 8 * U_;
        dp += 8 * U_;
    }

    // tail: t = 1017..1023 (7 steps); pf[0..6] hold rows 1017..1023
#pragma unroll
    for (int j = 0; j < 7; ++j) {
        const float m = maxplus_dpp(state, tr, lane, baddr);
        state = pf[j] + m;
        if (lane < U_) dp[j * U_] = state;
    }
}

// Fallback (in-place) variant if ws can't fit a second delta buffer.
__global__ __launch_bounds__(64, 1) void k_forward_inplace(const float* __restrict__ trans,
                                                           float* __restrict__ delta) {
    const int lane = threadIdx.x;
    const int b = blockIdx.x;
    const int u = (lane < U_) ? lane : (U_ - 1);
    const int baddr = ((lane + 32) & 63) * 4;

    float tr[64];
    load_tr(trans, tr, lane, u);

    float* base = delta + (long)b * T_ * U_;
    float state = base[u];

#pragma unroll 1
    for (int t = 1; t < T_; ++t) {
        const float logit = base[(long)t * U_ + u];
        const float m = maxplus_dpp(state, tr, lane, baddr);
        state = logit + m;
        if (lane < U_) base[(long)t * U_ + u] = state;
    }
}

// ---------------------------------------------------------------------------
// K3: backpointers (unchanged). Throughput-parallel (4092 waves).
// ---------------------------------------------------------------------------
#define BP_ROWS 32
__global__ __launch_bounds__(64, 1) void k_bp(const float* __restrict__ trans,
                                              const float* __restrict__ delta,
                                              unsigned char* __restrict__ bp) {
    __shared__ float sbuf[2][U_];         // row parity double buffer
    const int lane = threadIdx.x;
    const int u = (lane < U_) ? lane : (U_ - 1);

    float tc[U_];
#pragma unroll
    for (int v = 0; v < U_; ++v) tc[v] = trans[v * U_ + u];

    const int NROW = B_ * (T_ - 1);       // 130944
    const int row0 = blockIdx.x * BP_ROWS;
    if (row0 >= NROW) return;

    int b = row0 / (T_ - 1);              // uniform, once per block
    int tm1 = row0 - b * (T_ - 1);        // (t-1) in 0..1022

    float dval = delta[((long)b * T_ + tm1) * U_ + u];   // prefetch row0

#pragma unroll 1
    for (int i = 0; i < BP_ROWS; ++i) {
        const int row = row0 + i;
        if (row >= NROW) break;           // uniform guard

        sbuf[i & 1][u] = dval;            // stage current row (dup benign)

        // advance cursor, prefetch next row
        int bn = b, tn = tm1 + 1;
        if (tn == T_ - 1) { tn = 0; bn = b + 1; }
        float dnext = 0.0f;
        if (row + 1 < NROW) dnext = delta[((long)bn * T_ + tn) * U_ + u];

        const float4* sb4 = (const float4*)sbuf[i & 1];
        float best = -3.4e38f;
        int bi = 0;
#pragma unroll
        for (int k = 0; k < U_ / 4; ++k) {
            float4 s = sb4[k];            // uniform broadcast read
            float c0 = s.x + tc[4*k+0];
            float c1 = s.y + tc[4*k+1];
            float c2 = s.z + tc[4*k+2];
            float c3 = s.w + tc[4*k+3];
            bi = (c0 > best) ? 4*k+0 : bi;  best = fmaxf(best, c0);
            bi = (c1 > best) ? 4*k+1 : bi;  best = fmaxf(best, c1);
            bi = (c2 > best) ? 4*k+2 : bi;  best = fmaxf(best, c2);
            bi = (c3 > best) ? 4*k+3 : bi;  best = fmaxf(best, c3);
        }
        bp[(long)row * U_ + u] = (unsigned char)bi;   // dup-writes benign

        b = bn; tm1 = tn; dval = dnext;
    }
}

// ---------------------------------------------------------------------------
// K4: backtrace (unchanged this round).
// ---------------------------------------------------------------------------
__global__ __launch_bounds__(64) void k_back(const float* __restrict__ delta,
                                             const unsigned char* __restrict__ bp,
                                             float* __restrict__ out) {
    __shared__ unsigned char bpl[(T_ - 1) * U_];  // 49104 B
    __shared__ float tags[T_];                    // 4 KB
    __shared__ float fin[U_];
    const int lane = threadIdx.x;
    const int b = blockIdx.x;

    const uint32_t* src = (const uint32_t*)(bp + (long)b * (T_ - 1) * U_);
    uint32_t* dst = (uint32_t*)bpl;
    const int NW = (T_ - 1) * U_ / 4;             // 12276
    for (int i = lane; i < NW; i += 64) dst[i] = src[i];
    if (lane < U_) fin[lane] = delta[((long)b * T_ + (T_ - 1)) * U_ + lane];
    __syncthreads();

    if (lane == 0) {
        float best = fin[0];
        int tag = 0;
        for (int uu = 1; uu < U_; ++uu)
            if (fin[uu] > best) { best = fin[uu]; tag = uu; }
        tags[T_ - 1] = (float)tag;
        for (int t = T_ - 1; t >= 1; --t) {
            tag = bpl[(t - 1) * U_ + tag];
            tags[t - 1] = (float)tag;
        }
    }
    __syncthreads();

    float* o = out + (long)b * T_;
    for (int i = lane; i < T_; i += 64) o[i] = tags[i];
}

// ---------------------------------------------------------------------------
extern "C" void kernel_launch(void* const* d_in, const int* in_sizes, int n_in,
                              void* d_out, int out_size, void* d_ws, size_t ws_size,
                              hipStream_t stream) {
    const float* x     = (const float*)d_in[0];   // (B,T,D)
    const float* kern  = (const float*)d_in[1];   // (D,U)
    const float* bias  = (const float*)d_in[2];   // (U,)
    const float* trans = (const float*)d_in[3];   // (U,U)
    float* out = (float*)d_out;                   // (B,T) fp32 tags

    const size_t NBT = (size_t)B_ * T_ * U_ * sizeof(float);  // 25,165,824 B

    float* logits = (float*)d_ws;
    const bool two_buf = ws_size >= 2 * NBT + (size_t)B_ * T_ * U_;
    float* delta = two_buf ? (float*)((char*)d_ws + NBT) : logits;
    unsigned char* bp = (unsigned char*)d_ws + (two_buf ? 2 * NBT : NBT);

    const int NROW = B_ * (T_ - 1);
    const int bp_grid = (NROW + BP_ROWS - 1) / BP_ROWS;   // 4092

    k_logits<<<(B_ * T_ / 2) / 256, 256, 0, stream>>>(x, kern, bias, logits);
    if (two_buf)
        k_forward<<<B_, 64, 0, stream>>>(trans, logits, delta);
    else
        k_forward_inplace<<<B_, 64, 0, stream>>>(trans, logits);
    k_bp  <<<bp_grid, 64, 0, stream>>>(trans, delta, bp);
    k_back<<<B_,      64, 0, stream>>>(delta, bp, out);
}

// Round 6
// 500.432 us; speedup vs baseline: 1.4746x; 1.4746x over previous
//
#include <hip/hip_runtime.h>
#include <cstdint>

#define B_ 128
#define T_ 1024
#define D_ 256
#define U_ 48

typedef float v2f __attribute__((ext_vector_type(2)));

// Guaranteed packed fp32 add (2 IEEE adds, bit-identical to scalar v_add_f32).
__device__ __forceinline__ v2f pk_add(v2f a, v2f b) {
    v2f d;
    asm("v_pk_add_f32 %0, %1, %2" : "=v"(d) : "v"(a), "v"(b));
    return d;
}
// Guaranteed 3-input max (exact, same result as two v_max_f32).
__device__ __forceinline__ float max3f(float a, float b, float c) {
    float d;
    asm("v_max3_f32 %0, %1, %2, %3" : "=v"(d) : "v"(a), "v"(b), "v"(c));
    return d;
}

// ---------------------------------------------------------------------------
// K1: logits[row][u] = sum_d x[row][d]*kernel[d][u] + bias[u].
// (unchanged — d-blocked, K in LDS, own-line loads)
// ---------------------------------------------------------------------------
__global__ __launch_bounds__(256, 1) void k_logits(const float* __restrict__ x,
                                                   const float* __restrict__ kern,
                                                   const float* __restrict__ bias,
                                                   float* __restrict__ logits) {
    __shared__ float K[D_ * U_];   // 48 KB
    __shared__ float bsh[U_];
    const int tid = threadIdx.x;
    for (int i = tid; i < D_ * U_; i += 256) K[i] = kern[i];
    if (tid < U_) bsh[tid] = bias[tid];
    __syncthreads();

    const long row0 = (long)blockIdx.x * 256 + tid;      // 0..65535
    const long row1 = row0 + (long)B_ * T_ / 2;          // +65536
    const float4* xr0 = (const float4*)(x + row0 * D_);
    const float4* xr1 = (const float4*)(x + row1 * D_);

    float a0[U_], a1[U_];
#pragma unroll
    for (int u = 0; u < U_; ++u) { a0[u] = 0.0f; a1[u] = 0.0f; }

#pragma unroll 1
    for (int blk = 0; blk < D_ / 32; ++blk) {            // 8 chunks of 128 B
        float4 xa[8], xb[8];
#pragma unroll
        for (int i = 0; i < 8; ++i) xa[i] = xr0[blk * 8 + i];  // own line
#pragma unroll
        for (int i = 0; i < 8; ++i) xb[i] = xr1[blk * 8 + i];  // own line

#pragma unroll
        for (int i = 0; i < 8; ++i) {
            const int d4 = blk * 8 + i;
            const float xc0[4] = {xa[i].x, xa[i].y, xa[i].z, xa[i].w};
            const float xc1[4] = {xb[i].x, xb[i].y, xb[i].z, xb[i].w};
#pragma unroll
            for (int c = 0; c < 4; ++c) {
                const float4* kp = (const float4*)&K[(d4 * 4 + c) * U_];
                const float s0 = xc0[c], s1 = xc1[c];
#pragma unroll
                for (int u4 = 0; u4 < U_ / 4; ++u4) {
                    float4 kv = kp[u4];
                    a0[u4*4+0] += s0 * kv.x;  a1[u4*4+0] += s1 * kv.x;
                    a0[u4*4+1] += s0 * kv.y;  a1[u4*4+1] += s1 * kv.y;
                    a0[u4*4+2] += s0 * kv.z;  a1[u4*4+2] += s1 * kv.z;
                    a0[u4*4+3] += s0 * kv.w;  a1[u4*4+3] += s1 * kv.w;
                }
            }
        }
    }

    float4* o0 = (float4*)(logits + row0 * U_);
    float4* o1 = (float4*)(logits + row1 * U_);
#pragma unroll
    for (int i = 0; i < U_ / 4; ++i) {
        float4 v0, v1;
        v0.x = a0[i*4+0] + bsh[i*4+0];  v1.x = a1[i*4+0] + bsh[i*4+0];
        v0.y = a0[i*4+1] + bsh[i*4+1];  v1.y = a1[i*4+1] + bsh[i*4+1];
        v0.z = a0[i*4+2] + bsh[i*4+2];  v1.z = a1[i*4+2] + bsh[i*4+2];
        v0.w = a0[i*4+3] + bsh[i*4+3];  v1.w = a1[i*4+3] + bsh[i*4+3];
        o0[i] = v0;
        o1[i] = v1;
    }
}

// ---------------------------------------------------------------------------
// Max-plus body (R2-measured best: 215.5 µs): LDS broadcast (12x ds_read_b128
// uniform) + 24x v_pk_add_f32 + 24x v_max3_f32 tree. Candidates are a single
// IEEE add of the same operands as ref; max reassociation exact.
// ---------------------------------------------------------------------------
__device__ __forceinline__ float step_max_lds(const float4* sb, const v2f* tc2) {
    float4 s[12];
#pragma unroll
    for (int k = 0; k < 12; ++k) s[k] = sb[k];        // 12x ds_read_b128
    float cf[48];
#pragma unroll
    for (int k = 0; k < 12; ++k) {
        v2f lo, hi;
        lo.x = s[k].x; lo.y = s[k].y;
        hi.x = s[k].z; hi.y = s[k].w;
        v2f r0 = pk_add(lo, tc2[2 * k + 0]);
        v2f r1 = pk_add(hi, tc2[2 * k + 1]);
        cf[4*k+0] = r0.x; cf[4*k+1] = r0.y;
        cf[4*k+2] = r1.x; cf[4*k+3] = r1.y;
    }
    float t1[16];
#pragma unroll
    for (int i = 0; i < 16; ++i) t1[i] = max3f(cf[3*i], cf[3*i+1], cf[3*i+2]);
    float t2[6];
#pragma unroll
    for (int i = 0; i < 5; ++i) t2[i] = max3f(t1[3*i], t1[3*i+1], t1[3*i+2]);
    t2[5] = t1[15];
    const float a = max3f(t2[0], t2[1], t2[2]);
    const float b = max3f(t2[3], t2[4], t2[5]);
    return fmaxf(a, b);
}

// ---------------------------------------------------------------------------
// K2: Viterbi forward (R2 structure restored verbatim). One wave per chain.
// ---------------------------------------------------------------------------
__global__ __launch_bounds__(64, 1) void k_forward(const float* __restrict__ trans,
                                                   const float* __restrict__ logits,
                                                   float* __restrict__ delta) {
    __shared__ float4 sbuf[2][U_ / 4];    // parity double buffer, 2x48 floats
    const int lane = threadIdx.x;
    const int b = blockIdx.x;
    const int u = (lane < U_) ? lane : (U_ - 1);

    v2f tc2[U_ / 2];
#pragma unroll
    for (int v = 0; v < U_; v += 2) {
        tc2[v / 2].x = trans[v * U_ + u];
        tc2[v / 2].y = trans[(v + 1) * U_ + u];
    }

    const float* lin = logits + (long)b * T_ * U_;
    float* dout = delta + (long)b * T_ * U_;

    float state = lin[u];                 // delta_0 = logits row 0
    dout[u] = state;                      // dup-writes (lanes 48-63) benign
    ((float*)sbuf[0])[u] = state;         // t=0 parity 0

    float pf[8];
#pragma unroll
    for (int i = 0; i < 8; ++i) pf[i] = lin[(1 + i) * U_ + u];  // rows 1..8

    const float* lp = lin + 9 * U_ + u;   // prefetch base: row tb+8 for tb=1
    float* dp = dout + 1 * U_ + u;        // store base: row tb

#pragma unroll 1
    for (int g = 0; g < 127; ++g) {       // t = 1+8g .. 8+8g  (1..1016)
#pragma unroll
        for (int j = 0; j < 8; ++j) {
            const float logit = pf[j];
            pf[j] = lp[j * U_];                       // imm offset j*192 B

            const float4* sb = sbuf[j & 1];           // parity (t-1)&1 == j&1
            const float m = step_max_lds(sb, tc2);
            state = logit + m;                        // exact ref op order
            ((float*)sbuf[(j & 1) ^ 1])[u] = state;
            dp[j * U_] = state;                       // imm offset j*192 B
        }
        lp += 8 * U_;
        dp += 8 * U_;
    }

    // tail: t = 1017..1023 (7 steps); pf[0..6] hold rows 1017..1023
#pragma unroll
    for (int j = 0; j < 7; ++j) {
        const float logit = pf[j];
        const float4* sb = sbuf[j & 1];               // (t-1)=1016+j parity j&1
        const float m = step_max_lds(sb, tc2);
        state = logit + m;
        ((float*)sbuf[(j & 1) ^ 1])[u] = state;
        dp[j * U_] = state;
    }
}

// Fallback (in-place) variant if ws can't fit a second delta buffer.
__global__ __launch_bounds__(64, 1) void k_forward_inplace(const float* __restrict__ trans,
                                                           float* __restrict__ delta) {
    __shared__ float4 sbuf[2][U_ / 4];
    const int lane = threadIdx.x;
    const int b = blockIdx.x;
    const int u = (lane < U_) ? lane : (U_ - 1);

    v2f tc2[U_ / 2];
#pragma unroll
    for (int v = 0; v < U_; v += 2) {
        tc2[v / 2].x = trans[v * U_ + u];
        tc2[v / 2].y = trans[(v + 1) * U_ + u];
    }

    float* base = delta + (long)b * T_ * U_;
    float state = base[u];
    ((float*)sbuf[0])[u] = state;

#pragma unroll 1
    for (int t = 1; t < T_; ++t) {
        const float logit = base[(long)t * U_ + u];
        const float m = step_max_lds(sbuf[(t - 1) & 1], tc2);
        state = logit + m;
        ((float*)sbuf[t & 1])[u] = state;
        base[(long)t * U_ + u] = state;
    }
}

// ---------------------------------------------------------------------------
// K3: backpointers (unchanged). Throughput-parallel (4092 waves).
// ---------------------------------------------------------------------------
#define BP_ROWS 32
__global__ __launch_bounds__(64, 1) void k_bp(const float* __restrict__ trans,
                                              const float* __restrict__ delta,
                                              unsigned char* __restrict__ bp) {
    __shared__ float sbuf[2][U_];         // row parity double buffer
    const int lane = threadIdx.x;
    const int u = (lane < U_) ? lane : (U_ - 1);

    float tc[U_];
#pragma unroll
    for (int v = 0; v < U_; ++v) tc[v] = trans[v * U_ + u];

    const int NROW = B_ * (T_ - 1);       // 130944
    const int row0 = blockIdx.x * BP_ROWS;
    if (row0 >= NROW) return;

    int b = row0 / (T_ - 1);              // uniform, once per block
    int tm1 = row0 - b * (T_ - 1);        // (t-1) in 0..1022

    float dval = delta[((long)b * T_ + tm1) * U_ + u];   // prefetch row0

#pragma unroll 1
    for (int i = 0; i < BP_ROWS; ++i) {
        const int row = row0 + i;
        if (row >= NROW) break;           // uniform guard

        sbuf[i & 1][u] = dval;            // stage current row (dup benign)

        // advance cursor, prefetch next row
        int bn = b, tn = tm1 + 1;
        if (tn == T_ - 1) { tn = 0; bn = b + 1; }
        float dnext = 0.0f;
        if (row + 1 < NROW) dnext = delta[((long)bn * T_ + tn) * U_ + u];

        const float4* sb4 = (const float4*)sbuf[i & 1];
        float best = -3.4e38f;
        int bi = 0;
#pragma unroll
        for (int k = 0; k < U_ / 4; ++k) {
            float4 s = sb4[k];            // uniform broadcast read
            float c0 = s.x + tc[4*k+0];
            float c1 = s.y + tc[4*k+1];
            float c2 = s.z + tc[4*k+2];
            float c3 = s.w + tc[4*k+3];
            bi = (c0 > best) ? 4*k+0 : bi;  best = fmaxf(best, c0);
            bi = (c1 > best) ? 4*k+1 : bi;  best = fmaxf(best, c1);
            bi = (c2 > best) ? 4*k+2 : bi;  best = fmaxf(best, c2);
            bi = (c3 > best) ? 4*k+3 : bi;  best = fmaxf(best, c3);
        }
        bp[(long)row * U_ + u] = (unsigned char)bi;   // dup-writes benign

        b = bn; tm1 = tn; dval = dnext;
    }
}

// ---------------------------------------------------------------------------
// K4: backtrace, R12: blocked function composition. The old serial lane-0
// chase was 1023 dependent LDS reads (~120 cy each ~ 51 us). New: pad bp
// with identity row 1023 -> 1024 rows = 32 blocks x 32 rows.
//   Phase A: all (block, entry-tag) compositions in parallel (1536 chases of
//            32 hops; 6 interleaved chains per thread -> latency pipelined).
//   Phase B: serial composition across 32 block-maps (31 hops).
//   Phase C: 32 blocks re-chase in parallel with known entry tags, emit tags.
// Exact: same lookups as the serial chase; argmax reduce keeps first index
// on ties (== jnp.argmax).
// ---------------------------------------------------------------------------
#define KB_ 32
#define NB_ 32
__global__ __launch_bounds__(256) void k_back(const float* __restrict__ delta,
                                              const unsigned char* __restrict__ bp,
                                              float* __restrict__ out) {
    __shared__ unsigned char bpl[1024 * U_];      // 49152 B (row 1023 = identity)
    __shared__ unsigned char gmap[NB_ * U_];      // 1536 B: gmap[i][e] = exit tag
    __shared__ unsigned char eIn[NB_];            // entry tag per block
    __shared__ float tags[T_];                    // 4 KB
    __shared__ int Ash;
    const int tid = threadIdx.x;
    const int b = blockIdx.x;

    // stage bp rows 0..1022 (12276 dwords), identity row 1023
    const uint32_t* src = (const uint32_t*)(bp + (long)b * (T_ - 1) * U_);
    uint32_t* dst = (uint32_t*)bpl;
    const int NW = (T_ - 1) * U_ / 4;             // 12276
    for (int i = tid; i < NW; i += 256) dst[i] = src[i];
    if (tid < U_) bpl[1023 * U_ + tid] = (unsigned char)tid;

    // wave-parallel argmax of final delta row (first wave only)
    if (tid < 64) {
        const int lane = tid;
        float v = (lane < U_) ? delta[((long)b * T_ + (T_ - 1)) * U_ + lane] : -3.4e38f;
        int idx = (lane < U_) ? lane : 64;
#pragma unroll
        for (int off = 32; off >= 1; off >>= 1) {
            const float ov = __shfl_xor(v, off);
            const int oi = __shfl_xor(idx, off);
            if (ov > v || (ov == v && oi < idx)) { v = ov; idx = oi; }
        }
        if (lane == 0) Ash = idx;
    }
    __syncthreads();

    // Phase A: 1536 tasks = 6 chains/thread, hop-major interleave (6 LDS
    // reads in flight per thread -> dependent latency pipelined).
    int ik[6], ek[6], ck[6];
#pragma unroll
    for (int k = 0; k < 6; ++k) {
        const int tau = tid + k * 256;
        ik[k] = tau / U_;                 // block 0..31
        ek[k] = tau - ik[k] * U_;         // entry tag 0..47
        ck[k] = ek[k];
    }
#pragma unroll
    for (int h = 0; h < KB_; ++h) {
#pragma unroll
        for (int k = 0; k < 6; ++k) {
            const int r = ik[k] * KB_ + (KB_ - 1 - h);   // hi down to lo
            ck[k] = bpl[r * U_ + ck[k]];
        }
    }
#pragma unroll
    for (int k = 0; k < 6; ++k) gmap[ik[k] * U_ + ek[k]] = (unsigned char)ck[k];
    __syncthreads();

    // Phase B: serial composition over block maps (31 dependent LDS reads).
    if (tid == 0) {
        int cur = Ash;
        eIn[NB_ - 1] = (unsigned char)cur;
#pragma unroll 1
        for (int i = NB_ - 1; i >= 1; --i) {
            cur = gmap[i * U_ + cur];
            eIn[i - 1] = (unsigned char)cur;
        }
    }
    __syncthreads();

    // Phase C: 32 parallel re-chases with known entry tags, emit all tags.
    if (tid < NB_) {
        const int i = tid;
        int cur = eIn[i];
#pragma unroll
        for (int h = 0; h < KB_; ++h) {
            const int r = i * KB_ + (KB_ - 1 - h);
            cur = bpl[r * U_ + cur];
            tags[r] = (float)cur;
        }
    }
    __syncthreads();

    float* o = out + (long)b * T_;
    for (int i = tid; i < T_; i += 256) o[i] = tags[i];
}

// ---------------------------------------------------------------------------
extern "C" void kernel_launch(void* const* d_in, const int* in_sizes, int n_in,
                              void* d_out, int out_size, void* d_ws, size_t ws_size,
                              hipStream_t stream) {
    const float* x     = (const float*)d_in[0];   // (B,T,D)
    const float* kern  = (const float*)d_in[1];   // (D,U)
    const float* bias  = (const float*)d_in[2];   // (U,)
    const float* trans = (const float*)d_in[3];   // (U,U)
    float* out = (float*)d_out;                   // (B,T) fp32 tags

    const size_t NBT = (size_t)B_ * T_ * U_ * sizeof(float);  // 25,165,824 B

    float* logits = (float*)d_ws;
    const bool two_buf = ws_size >= 2 * NBT + (size_t)B_ * T_ * U_;
    float* delta = two_buf ? (float*)((char*)d_ws + NBT) : logits;
    unsigned char* bp = (unsigned char*)d_ws + (two_buf ? 2 * NBT : NBT);

    const int NROW = B_ * (T_ - 1);
    const int bp_grid = (NROW + BP_ROWS - 1) / BP_ROWS;   // 4092

    k_logits<<<(B_ * T_ / 2) / 256, 256, 0, stream>>>(x, kern, bias, logits);
    if (two_buf)
        k_forward<<<B_, 64, 0, stream>>>(trans, logits, delta);
    else
        k_forward_inplace<<<B_, 64, 0, stream>>>(trans, logits);
    k_bp  <<<bp_grid, 64, 0, stream>>>(trans, delta, bp);
    k_back<<<B_, 256, 0, stream>>>(delta, bp, out);
}